// Round 5
// baseline (83.256 us; speedup 1.0000x reference)
//
#include <hip/hip_runtime.h>
#include <math.h>

#define NB 32        // n_basis
#define ED 256       // embed_dim
#define BB 8         // batch
#define XX 4096      // grid points
#define AA 64        // atoms
#define EPS 1e-4f
#define LOG2E 1.44269504088896340736f
#define LN2   0.69314718055994530942f
#define PI_F  3.14159265358979323846f

// Single fused kernel: one block per (b,a) pair.
// 256 threads = 8 x-groups x 32 basis-lanes. Thread (x_off, s) accumulates
// pooled[s] over its contiguous 512-x slice; dist/wrho loads broadcast
// across the 32 s-lanes (2 distinct addrs per wave instr). Block tail:
// LDS reduce -> phi = log(norm*pooled+eps) -> 256-wide dot with W -> out.
// Trans-pipe-bound: 512 v_exp_f32 per thread ~ 4096 cyc/wave.
__global__ __launch_bounds__(256) void k_fused(
    const float* __restrict__ wrho,    // [B][X]
    const float* __restrict__ dist,    // [B][X][A]
    const float* __restrict__ gammas,  // [NB]
    const float* __restrict__ W,       // [ED][NB]
    float* __restrict__ out)           // [B][A][ED]
{
    constexpr int XPT = XX / 8;        // 512 x per thread
    const int bid = blockIdx.x;
    const int b = bid >> 6;
    const int a = bid & 63;
    const int t = threadIdx.x;
    const int s = t & 31;              // basis index (per-lane)
    const int g = t >> 5;              // x-group 0..7

    // per-lane constant: -gamma_s * log2(e)
    const float mg = -gammas[s] * LOG2E;

    const int xb = g * XPT;
    const float* dptr = dist + ((size_t)b * XX + xb) * AA + a;   // stride AA
    const float* wptr = wrho + (size_t)b * XX + xb;

    float acc = 0.f;
    for (int i0 = 0; i0 < XPT; i0 += 8) {
        // wrho: 2x float4 (broadcast across s-lanes); dist: 8 scalar broadcasts
        float4 wA = *(const float4*)(wptr + i0);
        float4 wB = *(const float4*)(wptr + i0 + 4);
        float d[8];
#pragma unroll
        for (int j = 0; j < 8; ++j) d[j] = dptr[(size_t)(i0 + j) * AA];
        float wv[8] = {wA.x, wA.y, wA.z, wA.w, wB.x, wB.y, wB.z, wB.w};
#pragma unroll
        for (int j = 0; j < 8; ++j) {
            float e = __builtin_amdgcn_exp2f(mg * (d[j] * d[j]));  // v_exp_f32
            acc = fmaf(wv[j], e, acc);
        }
    }

    // reduce the 8 x-groups per s
    __shared__ float red[8][NB + 1];
    __shared__ float phi[NB];
    red[g][s] = acc;
    __syncthreads();
    if (t < NB) {
        float sum = 0.f;
#pragma unroll
        for (int q = 0; q < 8; ++q) sum += red[q][t];    // banks (t+q)%32: conflict-free
        float gm = gammas[t];
        float norm = exp2f(1.5f * log2f(PI_F / gm));     // (pi/gamma)^1.5
        phi[t] = LN2 * log2f(fmaf(norm, sum, EPS));
    }
    __syncthreads();

    // out[b][a][t] = sum_s phi[s] * W[t][s]   (phi reads broadcast from LDS)
    const float4* Wv = (const float4*)(W + (size_t)t * NB);
    float r = 0.f;
#pragma unroll
    for (int q = 0; q < NB / 4; ++q) {
        float4 w4 = Wv[q];
        r = fmaf(w4.x, phi[q * 4 + 0], r);
        r = fmaf(w4.y, phi[q * 4 + 1], r);
        r = fmaf(w4.z, phi[q * 4 + 2], r);
        r = fmaf(w4.w, phi[q * 4 + 3], r);
    }
    out[((size_t)b * AA + a) * ED + t] = r;
}

extern "C" void kernel_launch(void* const* d_in, const int* in_sizes, int n_in,
                              void* d_out, int out_size, void* d_ws, size_t ws_size,
                              hipStream_t stream) {
    const float* wrho   = (const float*)d_in[0];
    const float* dist   = (const float*)d_in[1];
    const float* gammas = (const float*)d_in[2];
    const float* W      = (const float*)d_in[3];
    float* out = (float*)d_out;
    (void)d_ws; (void)ws_size; (void)in_sizes; (void)n_in; (void)out_size;

    k_fused<<<BB * AA, 256, 0, stream>>>(wrho, dist, gammas, W, out);
}